// Round 11
// baseline (156.802 us; speedup 1.0000x reference)
//
#include <hip/hip_runtime.h>
#include <cstdint>
#include <cstddef>

#define S_LEN 4096
#define HID   512
#define NHEAD 8
#define HD    64
// (1/sqrt(64)) * log2(e)
#define SCALE_LOG2E 0.1803368801111204f

typedef __bf16 bf16;
typedef __bf16 bf16x8 __attribute__((ext_vector_type(8)));
typedef __bf16 bf16x4 __attribute__((ext_vector_type(4)));
typedef float  f32x4  __attribute__((ext_vector_type(4)));

// ---------------- fused input conversion: X + 4 weights -> bf16 ----------------
__global__ __launch_bounds__(256) void cvt_in(
    const float* __restrict__ hs, const float* __restrict__ wq,
    const float* __restrict__ wk, const float* __restrict__ wv,
    const float* __restrict__ wo,
    bf16* __restrict__ xb, bf16* __restrict__ wqb, bf16* __restrict__ wkb,
    bf16* __restrict__ wvb, bf16* __restrict__ wob)
{
    int e = (blockIdx.x * 256 + threadIdx.x) * 4;
    const float* s; bf16* d; int o;
    if (e < 2 * 1024 * 1024) { s = hs; d = xb; o = e; }
    else {
        int t = e - 2 * 1024 * 1024;
        int wi = t >> 18;
        o = t & ((1 << 18) - 1);
        s = (wi == 0) ? wq : (wi == 1) ? wk : (wi == 2) ? wv : wo;
        d = (wi == 0) ? wqb : (wi == 1) ? wkb : (wi == 2) ? wvb : wob;
    }
    const float4 v = *(const float4*)(s + o);
    bf16x4 ob;
    ob[0] = (bf16)v.x; ob[1] = (bf16)v.y; ob[2] = (bf16)v.z; ob[3] = (bf16)v.w;
    *(bf16x4*)(d + o) = ob;
}

// ---------------- QKV GEMM, bf16 in, fused RoPE/transpose epilogue ----------------
__global__ __launch_bounds__(256) void gemm_qkv(
    const bf16* __restrict__ Xb,
    const bf16* __restrict__ W0, const bf16* __restrict__ W1, const bf16* __restrict__ W2,
    const float* __restrict__ cosT, const float* __restrict__ sinT,
    const int* __restrict__ nregp,
    bf16* __restrict__ Qh, bf16* __restrict__ Kh, bf16* __restrict__ Vt)
{
    const int z = blockIdx.z;
    const bf16* W = (z == 0) ? W0 : (z == 1 ? W1 : W2);
    const int m0 = blockIdx.y * 64, n0 = blockIdx.x * 128;
    __shared__ bf16 lA[64][8][8];
    __shared__ bf16 lB[128][8][8];
    __shared__ bf16 scratch[64][136];
    const int tid = threadIdx.x;
    const int lane = tid & 63, w = tid >> 6;
    const int l16 = lane & 15, lc = lane >> 4, l7 = lane & 7;
    const int wm = (w & 1) * 32, wn = (w >> 1) * 64;
    f32x4 acc[2][4] = {};

    for (int k0 = 0; k0 < HID; k0 += 64) {
        __syncthreads();
#pragma unroll
        for (int i = 0; i < 2; i++) {
            int uu = tid + 256 * i;
            int m = uu >> 3, c = uu & 7;
            *(bf16x8*)(&lA[m][c ^ (m & 7)][0]) =
                *(const bf16x8*)(Xb + (size_t)(m0 + m) * HID + k0 + 8 * c);
        }
#pragma unroll
        for (int i = 0; i < 4; i++) {
            int uu = tid + 256 * i;
            int m = uu >> 3, c = uu & 7;
            *(bf16x8*)(&lB[m][c ^ (m & 7)][0]) =
                *(const bf16x8*)(W + (size_t)(n0 + m) * HID + k0 + 8 * c);
        }
        __syncthreads();
#pragma unroll
        for (int ks = 0; ks < 2; ks++) {
            bf16x8 af[2], bfr[4];
#pragma unroll
            for (int i = 0; i < 2; i++)
                af[i]  = *(const bf16x8*)(&lA[wm + 16 * i + l16][(4 * ks + lc) ^ l7][0]);
#pragma unroll
            for (int j = 0; j < 4; j++)
                bfr[j] = *(const bf16x8*)(&lB[wn + 16 * j + l16][(4 * ks + lc) ^ l7][0]);
#pragma unroll
            for (int i = 0; i < 2; i++)
#pragma unroll
                for (int j = 0; j < 4; j++)
                    acc[i][j] = __builtin_amdgcn_mfma_f32_16x16x32_bf16(
                        af[i], bfr[j], acc[i][j], 0, 0, 0);
        }
    }

    if (z == 2) {
        const int h = (n0 + wn) >> 6;
#pragma unroll
        for (int i = 0; i < 2; i++) {
            const int s0r = m0 + wm + 16 * i + 4 * lc;
#pragma unroll
            for (int j = 0; j < 4; j++) {
                const int dl = 16 * j + l16;
                bf16x4 o;
#pragma unroll
                for (int r = 0; r < 4; r++) o[r] = (bf16)acc[i][j][r];
                *(bf16x4*)(Vt + ((size_t)(h * HD + dl)) * S_LEN + s0r) = o;
            }
        }
    } else {
        const int nreg = *nregp;
        bf16* dst = (z == 0) ? Qh : Kh;
#pragma unroll
        for (int i = 0; i < 2; i++) {
            const int sl0 = wm + 16 * i + 4 * lc;
#pragma unroll
            for (int r = 0; r < 4; r++) {
                const int s = m0 + sl0 + r;
                float c0 = 1.f, sn0 = 0.f, c1 = 1.f, sn1 = 0.f;
                if (s >= nreg) {
                    const int p = s - nreg;
                    c0  = cosT[(size_t)p * HD + l16];
                    sn0 = sinT[(size_t)p * HD + l16];
                    c1  = cosT[(size_t)p * HD + 16 + l16];
                    sn1 = sinT[(size_t)p * HD + 16 + l16];
                }
                const float x0 = acc[i][0][r], x1 = acc[i][1][r];
                const float x2 = acc[i][2][r], x3 = acc[i][3][r];
                bf16* row = &scratch[sl0 + r][wn];
                row[l16]      = (bf16)(x0 * c0 - x2 * sn0);
                row[l16 + 16] = (bf16)(x1 * c1 - x3 * sn1);
                row[l16 + 32] = (bf16)(x2 * c0 + x0 * sn0);
                row[l16 + 48] = (bf16)(x3 * c1 + x1 * sn1);
            }
        }
        __syncthreads();
        const int h0 = n0 >> 6;
#pragma unroll
        for (int i = 0; i < 4; i++) {
            int u = tid + 256 * i;
            int row = u >> 4, c = u & 15;
            bf16x8 val = *(const bf16x8*)(&scratch[row][c * 8]);
            *(bf16x8*)(dst + ((size_t)(h0 + (c >> 3)) * S_LEN + m0 + row) * HD +
                       (c & 7) * 8) = val;
        }
    }
}

// ---------------- Causal attention: 128 q-rows/block, shared K/V frags ---------
// r9 structure (each wave owns TWO 16-row q-groups; K and V fragments read
// ONCE per iter and feed both groups -> ~0.55x LDS bytes/work vs r8) but with
// __launch_bounds__(256,2): r9's (256,3) capped VGPR at ~170 against ~200 live
// -> hot-loop spills ate the win. 2-way key split (no empty chunks; partials
// halve to 16MB for the fused output GEMM). No-max softmax partials combine
// by addition (done in gemm_out_f).
__global__ __launch_bounds__(256, 2) void attn_part(
    const bf16* __restrict__ Qh, const bf16* __restrict__ Kh,
    const bf16* __restrict__ Vt, float* __restrict__ Opart,
    float* __restrict__ Lpart)
{
    const int h = blockIdx.x >> 1;
    const int ch = blockIdx.x & 1;
    const int qb = 31 - (int)blockIdx.y;     // longest-first (LPT)
    const int nkt = 2 * qb + 2;              // 64-key tiles
    const int kmid = nkt >> 1;
    const int k0 = ch ? kmid : 0;
    const int k1 = ch ? nkt : kmid;          // both chunks non-empty (len qb+1)
    const int tid = threadIdx.x;
    const int lane = tid & 63, w = tid >> 6;
    const int l16 = lane & 15, lc = lane >> 4, l7 = lane & 7;

    float* Op = Opart + ((size_t)((h * 32 + qb) * 2 + ch)) * 8192;
    float* Lp = Lpart + ((size_t)((h * 32 + qb) * 2 + ch)) * 128;

    __shared__ bf16 lK[2][64][8][8];         // 16 KiB
    __shared__ bf16 lV[2][64][8][8];         // 16 KiB
    __shared__ bf16 lPT[4][2][16][76];       // per-wave, per-group P^T (19 KiB)

    const bf16* Kb_ = Kh + (size_t)h * S_LEN * HD;
    const bf16* Vb_ = Vt + (size_t)h * HD * S_LEN;

    int srow[2], scol[2];
#pragma unroll
    for (int i = 0; i < 2; i++) {
        int uu = tid + 256 * i;
        srow[i] = uu >> 3;
        scol[i] = uu & 7;
    }

    // q fragments for both groups: rows qb*128 + g*64 + 16w + l16
    bf16x8 qf[2][2];
#pragma unroll
    for (int g = 0; g < 2; g++) {
        const bf16* qrow = Qh + (size_t)h * S_LEN * HD +
                           (size_t)(qb * 128 + g * 64 + 16 * w + l16) * HD;
        qf[g][0] = *(const bf16x8*)(qrow + 8 * lc);
        qf[g][1] = *(const bf16x8*)(qrow + 32 + 8 * lc);
    }
    f32x4 oacc[2][4] = {};
    float l_sum[2] = {0.f, 0.f};

    // prologue: stage tile k0 into buf 0
    {
        bf16x8 kr[2], vr[2];
#pragma unroll
        for (int i = 0; i < 2; i++) {
            kr[i] = *(const bf16x8*)(Kb_ + (size_t)(k0 * 64 + srow[i]) * HD + 8 * scol[i]);
            vr[i] = *(const bf16x8*)(Vb_ + (size_t)srow[i] * S_LEN + k0 * 64 + 8 * scol[i]);
        }
#pragma unroll
        for (int i = 0; i < 2; i++) {
            *(bf16x8*)(&lK[0][srow[i]][scol[i] ^ (srow[i] & 7)][0]) = kr[i];
            *(bf16x8*)(&lV[0][srow[i]][scol[i] ^ (srow[i] & 7)][0]) = vr[i];
        }
    }

    int cur = 0;
    for (int kt = k0; kt < k1; kt++) {
        __syncthreads();

        bf16x8 kr[2], vr[2];
        if (kt + 1 < k1) {
#pragma unroll
            for (int i = 0; i < 2; i++) {
                kr[i] = *(const bf16x8*)(Kb_ + (size_t)((kt + 1) * 64 + srow[i]) * HD +
                                         8 * scol[i]);
                vr[i] = *(const bf16x8*)(Vb_ + (size_t)srow[i] * S_LEN +
                                         (kt + 1) * 64 + 8 * scol[i]);
            }
        }

        // S phase: S^T = K Q^T for both groups off one kf read
        f32x4 s0[4] = {}, s1[4] = {};
#pragma unroll
        for (int ks = 0; ks < 2; ks++)
#pragma unroll
            for (int j = 0; j < 4; j++) {
                bf16x8 kf = *(const bf16x8*)(&lK[cur][16 * j + l16][(4 * ks + lc) ^ l7][0]);
                s0[j] = __builtin_amdgcn_mfma_f32_16x16x32_bf16(kf, qf[0][ks], s0[j], 0, 0, 0);
                s1[j] = __builtin_amdgcn_mfma_f32_16x16x32_bf16(kf, qf[1][ks], s1[j], 0, 0, 0);
            }

        // softmax (no-max; scores bounded) + P^T store, per group
        const bool near_diag = (kt >= nkt - 2);
#pragma unroll
        for (int g = 0; g < 2; g++) {
            const f32x4* sg = g ? s1 : s0;
            float pv[4][4];
#pragma unroll
            for (int j = 0; j < 4; j++)
#pragma unroll
                for (int r = 0; r < 4; r++)
                    pv[j][r] = __builtin_amdgcn_exp2f(sg[j][r] * SCALE_LOG2E);
            if (near_diag) {
                const int qg = qb * 128 + g * 64 + 16 * w + l16;
#pragma unroll
                for (int j = 0; j < 4; j++)
#pragma unroll
                    for (int r = 0; r < 4; r++) {
                        const int keyg = kt * 64 + 16 * j + 4 * lc + r;
                        if (keyg > qg) pv[j][r] = 0.f;
                    }
            }
#pragma unroll
            for (int j = 0; j < 4; j++)
                l_sum[g] += (pv[j][0] + pv[j][1]) + (pv[j][2] + pv[j][3]);
#pragma unroll
            for (int j = 0; j < 4; j++) {
                bf16x4 pp;
#pragma unroll
                for (int r = 0; r < 4; r++) pp[r] = (bf16)pv[j][r];
                *(bf16x4*)(&lPT[w][g][l16][16 * j + 4 * lc]) = pp;
            }
        }

        // PV phase: one vf read feeds both groups
        bf16x8 pb[2][2];
#pragma unroll
        for (int g = 0; g < 2; g++)
#pragma unroll
            for (int ks = 0; ks < 2; ks++)
                pb[g][ks] = *(const bf16x8*)(&lPT[w][g][l16][32 * ks + 8 * lc]);
#pragma unroll
        for (int ks = 0; ks < 2; ks++)
#pragma unroll
            for (int j = 0; j < 4; j++) {
                bf16x8 vf = *(const bf16x8*)(&lV[cur][16 * j + l16][(4 * ks + lc) ^ l7][0]);
                oacc[0][j] = __builtin_amdgcn_mfma_f32_16x16x32_bf16(
                    vf, pb[0][ks], oacc[0][j], 0, 0, 0);
                oacc[1][j] = __builtin_amdgcn_mfma_f32_16x16x32_bf16(
                    vf, pb[1][ks], oacc[1][j], 0, 0, 0);
            }

        if (kt + 1 < k1) {
#pragma unroll
            for (int i = 0; i < 2; i++) {
                *(bf16x8*)(&lK[cur ^ 1][srow[i]][scol[i] ^ (srow[i] & 7)][0]) = kr[i];
                *(bf16x8*)(&lV[cur ^ 1][srow[i]][scol[i] ^ (srow[i] & 7)][0]) = vr[i];
            }
        }
        cur ^= 1;
    }

    // l: combine 4 lc-replicas of each q; store per-group rows
#pragma unroll
    for (int g = 0; g < 2; g++) {
        float ls = l_sum[g];
        ls += __shfl_xor(ls, 16, 64);
        ls += __shfl_xor(ls, 32, 64);
        if (lane < 16) Lp[g * 64 + 16 * w + l16] = ls;
#pragma unroll
        for (int j = 0; j < 4; j++)
            *(f32x4*)(Op + (size_t)(g * 64 + 16 * w + l16) * 64 + 16 * j + 4 * lc) =
                oacc[g][j];
    }
}

// ---------------- output GEMM fused with partial-combine + normalize ----------
// A[s][h*64+d] = (Opart0 + Opart1)(h,s,d) / l(h,s), built during LDS staging
// (normalization commutes with the Wo contraction since l depends only on the
// (head, row) of the A element). Kills the attn_combine kernel.
__global__ __launch_bounds__(256) void gemm_out_f(
    const float* __restrict__ Opart, const float* __restrict__ Lpart,
    const bf16* __restrict__ Wb, float* __restrict__ Y)
{
    const int by = blockIdx.y;
    const int m0 = by * 64, n0 = blockIdx.x * 64;
    const int qb = by >> 1, qloc0 = (by & 1) * 64;
    __shared__ bf16 lA[64][8][8];
    __shared__ bf16 lB[64][8][8];
    __shared__ float Linv[8][64];
    const int tid = threadIdx.x;
    const int lane = tid & 63, w = tid >> 6;
    const int l16 = lane & 15, lc = lane >> 4, l7 = lane & 7;
    const int wm = (w & 1) * 32, wn = (w >> 1) * 32;

    // 1/l per (head, local row)
    for (int e = tid; e < 512; e += 256) {
        const int hh = e >> 6, m = e & 63;
        const float* Lp = Lpart + ((size_t)(hh * 32 + qb) * 2) * 128 + qloc0 + m;
        Linv[hh][m] = 1.0f / (Lp[0] + Lp[128]);
    }

    f32x4 acc[2][2] = {};
    for (int k0 = 0; k0 < HID; k0 += 64) {
        const int hh = k0 >> 6;
        const float* Ph = Opart + ((size_t)(hh * 32 + qb) * 2) * 8192;
        __syncthreads();                     // also covers Linv writes (first iter)
#pragma unroll
        for (int i = 0; i < 2; i++) {
            int uu = tid + 256 * i;
            int m = uu >> 3, c = uu & 7;
            const float* P0 = Ph + (size_t)(qloc0 + m) * 64 + 8 * c;
            const float inv = Linv[hh][m];
            bf16x8 o;
#pragma unroll
            for (int e2 = 0; e2 < 8; e2++)
                o[e2] = (bf16)((P0[e2] + P0[8192 + e2]) * inv);
            *(bf16x8*)(&lA[m][c ^ (m & 7)][0]) = o;
        }
#pragma unroll
        for (int i = 0; i < 2; i++) {
            int uu = tid + 256 * i;
            int m = uu >> 3, c = uu & 7;
            *(bf16x8*)(&lB[m][c ^ (m & 7)][0]) =
                *(const bf16x8*)(Wb + (size_t)(n0 + m) * HID + k0 + 8 * c);
        }
        __syncthreads();
#pragma unroll
        for (int ks = 0; ks < 2; ks++) {
            bf16x8 af[2], bfr[2];
#pragma unroll
            for (int i = 0; i < 2; i++) {
                af[i]  = *(const bf16x8*)(&lA[wm + 16 * i + l16][(4 * ks + lc) ^ l7][0]);
                bfr[i] = *(const bf16x8*)(&lB[wn + 16 * i + l16][(4 * ks + lc) ^ l7][0]);
            }
#pragma unroll
            for (int i = 0; i < 2; i++)
#pragma unroll
                for (int j = 0; j < 2; j++)
                    acc[i][j] = __builtin_amdgcn_mfma_f32_16x16x32_bf16(
                        af[i], bfr[j], acc[i][j], 0, 0, 0);
        }
    }
#pragma unroll
    for (int i = 0; i < 2; i++) {
        int row = m0 + wm + 16 * i + 4 * lc;
#pragma unroll
        for (int j = 0; j < 2; j++) {
            int col = n0 + wn + 16 * j + l16;
#pragma unroll
            for (int r = 0; r < 4; r++)
                Y[(size_t)(row + r) * HID + col] = acc[i][j][r];
        }
    }
}

// ---------------- launch ----------------
extern "C" void kernel_launch(void* const* d_in, const int* in_sizes, int n_in,
                              void* d_out, int out_size, void* d_ws, size_t ws_size,
                              hipStream_t stream) {
    const float* hs   = (const float*)d_in[0];
    const float* Wq   = (const float*)d_in[1];
    const float* Wk   = (const float*)d_in[2];
    const float* Wv   = (const float*)d_in[3];
    const float* Wo   = (const float*)d_in[4];
    const float* cosT = (const float*)d_in[5];
    const float* sinT = (const float*)d_in[6];
    const int*   nreg = (const int*)d_in[7];

    char* ws = (char*)d_ws;
    const size_t MiB = 1 << 20;
    bf16*  Qh    = (bf16*)(ws);                         // 0-4   [8][S][64]
    bf16*  Kh    = (bf16*)(ws + 4 * MiB);               // 4-8   [8][S][64]
    bf16*  Vt    = (bf16*)(ws + 8 * MiB);               // 8-12  [8][64][S]
    float* Opart = (float*)(ws + 16 * MiB);             // 16-32 (512 x 32KB)
    float* Lpart = (float*)(ws + 32 * MiB);             // 32-32.25
    bf16*  Xb    = (bf16*)(ws + 33 * MiB);              // 33-37 hidden bf16
    bf16*  Wqb   = (bf16*)(ws + 37 * MiB);
    bf16*  Wkb   = (bf16*)(ws + 37 * MiB + 512 * 1024);
    bf16*  Wvb   = (bf16*)(ws + 38 * MiB);
    bf16*  Wob   = (bf16*)(ws + 38 * MiB + 512 * 1024);

    cvt_in<<<3072, 256, 0, stream>>>(hs, Wq, Wk, Wv, Wo, Xb, Wqb, Wkb, Wvb, Wob);
    gemm_qkv<<<dim3(4, 64, 3), 256, 0, stream>>>(Xb, Wqb, Wkb, Wvb,
                                                 cosT, sinT, nreg, Qh, Kh, Vt);
    attn_part<<<dim3(16, 32), 256, 0, stream>>>(Qh, Kh, Vt, Opart, Lpart);
    gemm_out_f<<<dim3(8, 64), 256, 0, stream>>>(Opart, Lpart, Wob, (float*)d_out);
}

// Round 12
// 135.710 us; speedup vs baseline: 1.1554x; 1.1554x over previous
//
#include <hip/hip_runtime.h>
#include <cstdint>
#include <cstddef>

#define S_LEN 4096
#define HID   512
#define NHEAD 8
#define HD    64
// (1/sqrt(64)) * log2(e)
#define SCALE_LOG2E 0.1803368801111204f

typedef __bf16 bf16;
typedef __bf16 bf16x8 __attribute__((ext_vector_type(8)));
typedef __bf16 bf16x4 __attribute__((ext_vector_type(4)));
typedef float  f32x4  __attribute__((ext_vector_type(4)));

// ---------------- fused input conversion: X + 4 weights -> bf16 ----------------
__global__ __launch_bounds__(256) void cvt_in(
    const float* __restrict__ hs, const float* __restrict__ wq,
    const float* __restrict__ wk, const float* __restrict__ wv,
    const float* __restrict__ wo,
    bf16* __restrict__ xb, bf16* __restrict__ wqb, bf16* __restrict__ wkb,
    bf16* __restrict__ wvb, bf16* __restrict__ wob)
{
    int e = (blockIdx.x * 256 + threadIdx.x) * 4;
    const float* s; bf16* d; int o;
    if (e < 2 * 1024 * 1024) { s = hs; d = xb; o = e; }
    else {
        int t = e - 2 * 1024 * 1024;
        int wi = t >> 18;
        o = t & ((1 << 18) - 1);
        s = (wi == 0) ? wq : (wi == 1) ? wk : (wi == 2) ? wv : wo;
        d = (wi == 0) ? wqb : (wi == 1) ? wkb : (wi == 2) ? wvb : wob;
    }
    const float4 v = *(const float4*)(s + o);
    bf16x4 ob;
    ob[0] = (bf16)v.x; ob[1] = (bf16)v.y; ob[2] = (bf16)v.z; ob[3] = (bf16)v.w;
    *(bf16x4*)(d + o) = ob;
}

// ---------------- QKV GEMM, bf16 in, fused RoPE/transpose epilogue ----------------
__global__ __launch_bounds__(256) void gemm_qkv(
    const bf16* __restrict__ Xb,
    const bf16* __restrict__ W0, const bf16* __restrict__ W1, const bf16* __restrict__ W2,
    const float* __restrict__ cosT, const float* __restrict__ sinT,
    const int* __restrict__ nregp,
    bf16* __restrict__ Qh, bf16* __restrict__ Kh, bf16* __restrict__ Vt)
{
    const int z = blockIdx.z;
    const bf16* W = (z == 0) ? W0 : (z == 1 ? W1 : W2);
    const int m0 = blockIdx.y * 64, n0 = blockIdx.x * 128;
    __shared__ bf16 lA[64][8][8];
    __shared__ bf16 lB[128][8][8];
    __shared__ bf16 scratch[64][136];
    const int tid = threadIdx.x;
    const int lane = tid & 63, w = tid >> 6;
    const int l16 = lane & 15, lc = lane >> 4, l7 = lane & 7;
    const int wm = (w & 1) * 32, wn = (w >> 1) * 64;
    f32x4 acc[2][4] = {};

    for (int k0 = 0; k0 < HID; k0 += 64) {
        __syncthreads();
#pragma unroll
        for (int i = 0; i < 2; i++) {
            int uu = tid + 256 * i;
            int m = uu >> 3, c = uu & 7;
            *(bf16x8*)(&lA[m][c ^ (m & 7)][0]) =
                *(const bf16x8*)(Xb + (size_t)(m0 + m) * HID + k0 + 8 * c);
        }
#pragma unroll
        for (int i = 0; i < 4; i++) {
            int uu = tid + 256 * i;
            int m = uu >> 3, c = uu & 7;
            *(bf16x8*)(&lB[m][c ^ (m & 7)][0]) =
                *(const bf16x8*)(W + (size_t)(n0 + m) * HID + k0 + 8 * c);
        }
        __syncthreads();
#pragma unroll
        for (int ks = 0; ks < 2; ks++) {
            bf16x8 af[2], bfr[4];
#pragma unroll
            for (int i = 0; i < 2; i++)
                af[i]  = *(const bf16x8*)(&lA[wm + 16 * i + l16][(4 * ks + lc) ^ l7][0]);
#pragma unroll
            for (int j = 0; j < 4; j++)
                bfr[j] = *(const bf16x8*)(&lB[wn + 16 * j + l16][(4 * ks + lc) ^ l7][0]);
#pragma unroll
            for (int i = 0; i < 2; i++)
#pragma unroll
                for (int j = 0; j < 4; j++)
                    acc[i][j] = __builtin_amdgcn_mfma_f32_16x16x32_bf16(
                        af[i], bfr[j], acc[i][j], 0, 0, 0);
        }
    }

    if (z == 2) {
        const int h = (n0 + wn) >> 6;
#pragma unroll
        for (int i = 0; i < 2; i++) {
            const int s0r = m0 + wm + 16 * i + 4 * lc;
#pragma unroll
            for (int j = 0; j < 4; j++) {
                const int dl = 16 * j + l16;
                bf16x4 o;
#pragma unroll
                for (int r = 0; r < 4; r++) o[r] = (bf16)acc[i][j][r];
                *(bf16x4*)(Vt + ((size_t)(h * HD + dl)) * S_LEN + s0r) = o;
            }
        }
    } else {
        const int nreg = *nregp;
        bf16* dst = (z == 0) ? Qh : Kh;
#pragma unroll
        for (int i = 0; i < 2; i++) {
            const int sl0 = wm + 16 * i + 4 * lc;
#pragma unroll
            for (int r = 0; r < 4; r++) {
                const int s = m0 + sl0 + r;
                float c0 = 1.f, sn0 = 0.f, c1 = 1.f, sn1 = 0.f;
                if (s >= nreg) {
                    const int p = s - nreg;
                    c0  = cosT[(size_t)p * HD + l16];
                    sn0 = sinT[(size_t)p * HD + l16];
                    c1  = cosT[(size_t)p * HD + 16 + l16];
                    sn1 = sinT[(size_t)p * HD + 16 + l16];
                }
                const float x0 = acc[i][0][r], x1 = acc[i][1][r];
                const float x2 = acc[i][2][r], x3 = acc[i][3][r];
                bf16* row = &scratch[sl0 + r][wn];
                row[l16]      = (bf16)(x0 * c0 - x2 * sn0);
                row[l16 + 16] = (bf16)(x1 * c1 - x3 * sn1);
                row[l16 + 32] = (bf16)(x2 * c0 + x0 * sn0);
                row[l16 + 48] = (bf16)(x3 * c1 + x1 * sn1);
            }
        }
        __syncthreads();
        const int h0 = n0 >> 6;
#pragma unroll
        for (int i = 0; i < 4; i++) {
            int u = tid + 256 * i;
            int row = u >> 4, c = u & 15;
            bf16x8 val = *(const bf16x8*)(&scratch[row][c * 8]);
            *(bf16x8*)(dst + ((size_t)(h0 + (c >> 3)) * S_LEN + m0 + row) * HD +
                       (c & 7) * 8) = val;
        }
    }
}

// ---------------- output GEMM: bf16 A x bf16 W, fp32 out ----------
__global__ __launch_bounds__(256) void gemm_out(
    const bf16* __restrict__ X, const bf16* __restrict__ Wb,
    float* __restrict__ Y)
{
    const int m0 = blockIdx.y * 64, n0 = blockIdx.x * 64;
    __shared__ bf16 lA[64][8][8];
    __shared__ bf16 lB[64][8][8];
    const int tid = threadIdx.x;
    const int lane = tid & 63, w = tid >> 6;
    const int l16 = lane & 15, lc = lane >> 4, l7 = lane & 7;
    const int wm = (w & 1) * 32, wn = (w >> 1) * 32;
    f32x4 acc[2][2] = {};

    for (int k0 = 0; k0 < HID; k0 += 64) {
        __syncthreads();
#pragma unroll
        for (int i = 0; i < 2; i++) {
            int uu = tid + 256 * i;
            int m = uu >> 3, c = uu & 7;
            *(bf16x8*)(&lA[m][c ^ (m & 7)][0]) =
                *(const bf16x8*)(X + (size_t)(m0 + m) * HID + k0 + 8 * c);
        }
#pragma unroll
        for (int i = 0; i < 2; i++) {
            int uu = tid + 256 * i;
            int m = uu >> 3, c = uu & 7;
            *(bf16x8*)(&lB[m][c ^ (m & 7)][0]) =
                *(const bf16x8*)(Wb + (size_t)(n0 + m) * HID + k0 + 8 * c);
        }
        __syncthreads();
#pragma unroll
        for (int ks = 0; ks < 2; ks++) {
            bf16x8 af[2], bfr[2];
#pragma unroll
            for (int i = 0; i < 2; i++) {
                af[i]  = *(const bf16x8*)(&lA[wm + 16 * i + l16][(4 * ks + lc) ^ l7][0]);
                bfr[i] = *(const bf16x8*)(&lB[wn + 16 * i + l16][(4 * ks + lc) ^ l7][0]);
            }
#pragma unroll
            for (int i = 0; i < 2; i++)
#pragma unroll
                for (int j = 0; j < 2; j++)
                    acc[i][j] = __builtin_amdgcn_mfma_f32_16x16x32_bf16(
                        af[i], bfr[j], acc[i][j], 0, 0, 0);
        }
    }
#pragma unroll
    for (int i = 0; i < 2; i++) {
        int row = m0 + wm + 16 * i + 4 * lc;
#pragma unroll
        for (int j = 0; j < 2; j++) {
            int col = n0 + wn + 16 * j + l16;
#pragma unroll
            for (int r = 0; r < 4; r++)
                Y[(size_t)(row + r) * HID + col] = acc[i][j][r];
        }
    }
}

// ---------------- Causal attention: single-buffered K/V for 6 blocks/CU ----------
// r8-r11 evidence: every pipe <30% busy, so attn is latency-bound and scales
// with co-resident independent blocks (r11's 2/CU regressed vs r8's 3/CU).
// Single-buffer K/V (8+8 KB) + lPT (9.5 KB) = ~26 KB LDS -> SIX blocks/CU
// (24 waves) vs r8's 3. Costs 2 barriers/iter; with 6 independent blocks per
// CU the barrier stalls are hidden. Global prefetch of tile t+1 issues right
// after the staging barrier. 4-way key split, no-max softmax, partials
// combine by addition.
__global__ __launch_bounds__(256) void attn_part(
    const bf16* __restrict__ Qh, const bf16* __restrict__ Kh,
    const bf16* __restrict__ Vt, float* __restrict__ Opart,
    float* __restrict__ Lpart)
{
    const int h = blockIdx.x >> 2;
    const int ch = blockIdx.x & 3;
    const int bt = 63 - (int)blockIdx.y;     // longest-first (LPT)
    const int qb = bt * 64;
    const int nkt = bt + 1;
    const int k0 = (nkt * ch) >> 2;
    const int k1 = (nkt * (ch + 1)) >> 2;
    const int tid = threadIdx.x;
    const int lane = tid & 63, w = tid >> 6;
    const int l16 = lane & 15, lc = lane >> 4, l7 = lane & 7;

    float* Op = Opart + ((size_t)(h * 64 + bt) * 4 + ch) * 4096;
    float* Lp = Lpart + ((size_t)(h * 64 + bt) * 4 + ch) * 64;

    if (k0 >= k1) {                          // empty chunk (small bt)
        const f32x4 z = {0.f, 0.f, 0.f, 0.f};
#pragma unroll
        for (int i = 0; i < 4; i++)
            *(f32x4*)(Op + 4 * (tid + 256 * i)) = z;
        if (tid < 64) Lp[tid] = 0.f;
        return;
    }

    __shared__ bf16 lK[64][8][8];            // 8 KiB (single buffer)
    __shared__ bf16 lV[64][8][8];            // 8 KiB
    __shared__ bf16 lPT[4][16][76];          // 9.5 KiB

    const bf16* Kb_ = Kh + (size_t)h * S_LEN * HD;
    const bf16* Vb_ = Vt + (size_t)h * HD * S_LEN;

    int srow[2], scol[2];
#pragma unroll
    for (int i = 0; i < 2; i++) {
        int uu = tid + 256 * i;
        srow[i] = uu >> 3;
        scol[i] = uu & 7;
    }

    bf16x8 qf[2];
    {
        const bf16* qrow = Qh + (size_t)h * S_LEN * HD + (size_t)(qb + 16 * w + l16) * HD;
        qf[0] = *(const bf16x8*)(qrow + 8 * lc);
        qf[1] = *(const bf16x8*)(qrow + 32 + 8 * lc);
    }
    f32x4 oacc[4] = {};
    float l_sum = 0.f;

    // prologue: load tile k0 into regs
    bf16x8 kr[2], vr[2];
#pragma unroll
    for (int i = 0; i < 2; i++) {
        kr[i] = *(const bf16x8*)(Kb_ + (size_t)(k0 * 64 + srow[i]) * HD + 8 * scol[i]);
        vr[i] = *(const bf16x8*)(Vb_ + (size_t)srow[i] * S_LEN + k0 * 64 + 8 * scol[i]);
    }

    for (int kt = k0; kt < k1; kt++) {
        // stage current tile regs -> LDS
#pragma unroll
        for (int i = 0; i < 2; i++) {
            *(bf16x8*)(&lK[srow[i]][scol[i] ^ (srow[i] & 7)][0]) = kr[i];
            *(bf16x8*)(&lV[srow[i]][scol[i] ^ (srow[i] & 7)][0]) = vr[i];
        }
        __syncthreads();                     // staging visible to all waves

        // prefetch next tile into regs (latency hidden behind compute)
        if (kt + 1 < k1) {
#pragma unroll
            for (int i = 0; i < 2; i++) {
                kr[i] = *(const bf16x8*)(Kb_ + (size_t)((kt + 1) * 64 + srow[i]) * HD +
                                         8 * scol[i]);
                vr[i] = *(const bf16x8*)(Vb_ + (size_t)srow[i] * S_LEN +
                                         (kt + 1) * 64 + 8 * scol[i]);
            }
        }

        // S^T = K Q^T
        f32x4 sacc[4] = {};
#pragma unroll
        for (int ks = 0; ks < 2; ks++)
#pragma unroll
            for (int j = 0; j < 4; j++) {
                bf16x8 kf = *(const bf16x8*)(&lK[16 * j + l16][(4 * ks + lc) ^ l7][0]);
                sacc[j] = __builtin_amdgcn_mfma_f32_16x16x32_bf16(
                    kf, qf[ks], sacc[j], 0, 0, 0);
            }

        float pv[4][4];
#pragma unroll
        for (int j = 0; j < 4; j++)
#pragma unroll
            for (int r = 0; r < 4; r++)
                pv[j][r] = __builtin_amdgcn_exp2f(sacc[j][r] * SCALE_LOG2E);
        if (kt == nkt - 1) {                 // diagonal tile
            const int qg = qb + 16 * w + l16;
#pragma unroll
            for (int j = 0; j < 4; j++)
#pragma unroll
                for (int r = 0; r < 4; r++) {
                    const int keyg = kt * 64 + 16 * j + 4 * lc + r;
                    if (keyg > qg) pv[j][r] = 0.f;
                }
        }
#pragma unroll
        for (int j = 0; j < 4; j++)
            l_sum += (pv[j][0] + pv[j][1]) + (pv[j][2] + pv[j][3]);

        // P^T -> per-wave LDS (no barrier needed: per-wave region)
#pragma unroll
        for (int j = 0; j < 4; j++) {
            bf16x4 pp;
#pragma unroll
            for (int r = 0; r < 4; r++) pp[r] = (bf16)pv[j][r];
            *(bf16x4*)(&lPT[w][l16][16 * j + 4 * lc]) = pp;
        }
        bf16x8 pb[2];
#pragma unroll
        for (int ks = 0; ks < 2; ks++)
            pb[ks] = *(const bf16x8*)(&lPT[w][l16][32 * ks + 8 * lc]);

        // O^T += V^T P^T
#pragma unroll
        for (int ks = 0; ks < 2; ks++)
#pragma unroll
            for (int j = 0; j < 4; j++) {
                bf16x8 vf = *(const bf16x8*)(&lV[16 * j + l16][(4 * ks + lc) ^ l7][0]);
                oacc[j] = __builtin_amdgcn_mfma_f32_16x16x32_bf16(
                    vf, pb[ks], oacc[j], 0, 0, 0);
            }

        __syncthreads();                     // K/V reads done; next iter may overwrite
    }

    // l: combine 4 lc-replicas of each q
    l_sum += __shfl_xor(l_sum, 16, 64);
    l_sum += __shfl_xor(l_sum, 32, 64);
    if (lane < 16) Lp[16 * w + l16] = l_sum;

    // unnormalized O^T partial: Op[q*64+d]
#pragma unroll
    for (int j = 0; j < 4; j++)
        *(f32x4*)(Op + (size_t)(16 * w + l16) * 64 + 16 * j + 4 * lc) = oacc[j];
}

// combine: O = (O0+O1+O2+O3)/(l0+l1+l2+l3) -> bf16 Ob[s][h*64+d]
__global__ __launch_bounds__(256) void attn_combine(
    const float* __restrict__ Opart, const float* __restrict__ Lpart,
    bf16* __restrict__ Ob)
{
    const int h = blockIdx.x, bt = blockIdx.y;
    const size_t base = (size_t)(h * 64 + bt) * 4;
    const float* O0 = Opart + base * 4096;
    const float* L0 = Lpart + base * 64;
    const int t = threadIdx.x;
    const int q = t >> 2, dq = (t & 3) * 16;
    const float l = (L0[q] + L0[64 + q]) + (L0[128 + q] + L0[192 + q]);
    const float inv = 1.0f / l;
    bf16* out = Ob + (size_t)(bt * 64 + q) * HID + h * HD + dq;
#pragma unroll
    for (int g = 0; g < 2; g++) {
        bf16x8 o8;
#pragma unroll
        for (int e = 0; e < 2; e++) {
            const int off = q * 64 + dq + 8 * g + 4 * e;
            f32x4 a = *(const f32x4*)(O0 + off);
            f32x4 b = *(const f32x4*)(O0 + 4096 + off);
            f32x4 c = *(const f32x4*)(O0 + 8192 + off);
            f32x4 d = *(const f32x4*)(O0 + 12288 + off);
#pragma unroll
            for (int r = 0; r < 4; r++)
                o8[4 * e + r] = (bf16)(((a[r] + b[r]) + (c[r] + d[r])) * inv);
        }
        *(bf16x8*)(out + 8 * g) = o8;
    }
}

// ---------------- launch ----------------
extern "C" void kernel_launch(void* const* d_in, const int* in_sizes, int n_in,
                              void* d_out, int out_size, void* d_ws, size_t ws_size,
                              hipStream_t stream) {
    const float* hs   = (const float*)d_in[0];
    const float* Wq   = (const float*)d_in[1];
    const float* Wk   = (const float*)d_in[2];
    const float* Wv   = (const float*)d_in[3];
    const float* Wo   = (const float*)d_in[4];
    const float* cosT = (const float*)d_in[5];
    const float* sinT = (const float*)d_in[6];
    const int*   nreg = (const int*)d_in[7];

    char* ws = (char*)d_ws;
    const size_t MiB = 1 << 20;
    bf16*  Qh    = (bf16*)(ws);                         // 0-4   [8][S][64]
    bf16*  Kh    = (bf16*)(ws + 4 * MiB);               // 4-8   [8][S][64]
    bf16*  Vt    = (bf16*)(ws + 8 * MiB);               // 8-12  [8][64][S]
    bf16*  Ob    = (bf16*)(ws + 12 * MiB);              // 12-16 [S][512]
    float* Opart = (float*)(ws + 16 * MiB);             // 16-48 (2048 x 16KB)
    float* Lpart = (float*)(ws + 48 * MiB);             // 48-48.5
    bf16*  Xb    = (bf16*)(ws + 49 * MiB);              // 49-53 hidden bf16
    bf16*  Wqb   = (bf16*)(ws + 53 * MiB);
    bf16*  Wkb   = (bf16*)(ws + 53 * MiB + 512 * 1024);
    bf16*  Wvb   = (bf16*)(ws + 54 * MiB);
    bf16*  Wob   = (bf16*)(ws + 54 * MiB + 512 * 1024);

    cvt_in<<<3072, 256, 0, stream>>>(hs, Wq, Wk, Wv, Wo, Xb, Wqb, Wkb, Wvb, Wob);
    gemm_qkv<<<dim3(4, 64, 3), 256, 0, stream>>>(Xb, Wqb, Wkb, Wvb,
                                                 cosT, sinT, nreg, Qh, Kh, Vt);
    attn_part<<<dim3(32, 64), 256, 0, stream>>>(Qh, Kh, Vt, Opart, Lpart);
    attn_combine<<<dim3(8, 64), 256, 0, stream>>>(Opart, Lpart, Ob);
    gemm_out<<<dim3(8, 64), 256, 0, stream>>>(Ob, Wob, (float*)d_out);
}